// Round 1
// baseline (1822.495 us; speedup 1.0000x reference)
//
#include <hip/hip_runtime.h>

#define B_TOT 4096
#define N_TOK 49
#define C_DIM 128
#define HD 32
#define NW_WIN 64
#define SCALE 0.17677669529663687f
#define PAD33 33
#define S_PAD 57

// Kernel 1: per (b, h) attention. Writes pre-projection activations to
// act[b][n][h*HD + d]  (== concat-head layout the proj kernel consumes).
__global__ __launch_bounds__(256) void attn_fused(
    const float* __restrict__ x,
    const float* __restrict__ mask,
    const float* __restrict__ qkv_w,
    const float* __restrict__ qkv_b,
    float* __restrict__ act)
{
    const int b   = blockIdx.x;
    const int h   = blockIdx.y;
    const int tid = threadIdx.x;

    // xs: staged x[b] (49x128). Reused as S (49 x S_PAD) in phase B.
    __shared__ __align__(16) float xs[N_TOK * C_DIM];   // 6272 floats
    __shared__ __align__(16) float wT[C_DIM * PAD33];   // wT[kk][j], pad-33
    __shared__ float qs[N_TOK * PAD33];                 // [n][d], pad-33
    __shared__ float ks[N_TOK * PAD33];
    __shared__ float vs[N_TOK * PAD33];

    // ---- stage x[b] (coalesced float4) ----
    {
        const float4* xg  = (const float4*)(x + (size_t)b * N_TOK * C_DIM);
        float4*       xs4 = (float4*)xs;
        for (int i = tid; i < N_TOK * C_DIM / 4; i += 256) xs4[i] = xg[i];
    }
    __syncthreads();

    const int tx = tid & 31;   // head channel d
    const int ty = tid >> 5;   // row group 0..7
    int row[7], rwc[7];
#pragma unroll
    for (int r = 0; r < 7; ++r) {
        row[r] = ty + 8 * r;
        rwc[r] = row[r] < N_TOK ? row[r] : N_TOK - 1;  // clamp for safe LDS reads
    }

    // ---- phase A: q/k/v = x @ w_head^T (+bias) ----
    for (int m = 0; m < 3; ++m) {
        // stage wT[kk][j] = qkv_w[m*128 + h*32 + j][kk]; coalesced global read,
        // transposed LDS write (pad-33 keeps write conflicts ~8-way, reads clean)
        const float4* wg = (const float4*)(qkv_w + ((size_t)m * C_DIM + h * HD) * C_DIM);
        for (int i = tid; i < HD * C_DIM / 4; i += 256) {
            int j  = i >> 5;          // output channel 0..31
            int kk = (i & 31) << 2;   // k offset
            float4 wv = wg[i];
            wT[(kk + 0) * PAD33 + j] = wv.x;
            wT[(kk + 1) * PAD33 + j] = wv.y;
            wT[(kk + 2) * PAD33 + j] = wv.z;
            wT[(kk + 3) * PAD33 + j] = wv.w;
        }
        __syncthreads();

        float acc[7] = {0.f, 0.f, 0.f, 0.f, 0.f, 0.f, 0.f};
        for (int kk = 0; kk < C_DIM; kk += 4) {
            // conflict-free: lanes tx consecutive -> consecutive banks
            float w0 = wT[(kk + 0) * PAD33 + tx];
            float w1 = wT[(kk + 1) * PAD33 + tx];
            float w2 = wT[(kk + 2) * PAD33 + tx];
            float w3 = wT[(kk + 3) * PAD33 + tx];
#pragma unroll
            for (int r = 0; r < 7; ++r) {
                // broadcast within half-wave (same row address)
                float4 xv = *(const float4*)&xs[rwc[r] * C_DIM + kk];
                acc[r] = fmaf(xv.x, w0, acc[r]);
                acc[r] = fmaf(xv.y, w1, acc[r]);
                acc[r] = fmaf(xv.z, w2, acc[r]);
                acc[r] = fmaf(xv.w, w3, acc[r]);
            }
        }
        float bias = qkv_b[m * C_DIM + h * HD + tx];
        float* dst = (m == 0) ? qs : (m == 1 ? ks : vs);
        float sc   = (m == 0) ? SCALE : 1.f;
#pragma unroll
        for (int r = 0; r < 7; ++r)
            if (row[r] < N_TOK) dst[row[r] * PAD33 + tx] = (acc[r] + bias) * sc;
        __syncthreads();  // wT reused next m; also fences last xs reads before S reuse
    }

    // ---- phase B: S = q k^T + mask ----
    float* S = xs;  // reuse (49 * 57 = 2793 <= 6272)
    const float* mk = mask + (size_t)(b & (NW_WIN - 1)) * N_TOK * N_TOK;
    for (int idx = tid; idx < N_TOK * N_TOK; idx += 256) {
        int i = idx / N_TOK, j = idx - i * N_TOK;
        float s = 0.f;
#pragma unroll
        for (int kk = 0; kk < HD; ++kk)
            s = fmaf(qs[i * PAD33 + kk], ks[j * PAD33 + kk], s);
        S[i * S_PAD + j] = s + mk[idx];
    }
    __syncthreads();

    // ---- softmax rows (49 threads; tiny) ----
    if (tid < N_TOK) {
        float mx = -1e30f;
        for (int j = 0; j < N_TOK; ++j) mx = fmaxf(mx, S[tid * S_PAD + j]);
        float sum = 0.f;
        for (int j = 0; j < N_TOK; ++j) {
            float e = __expf(S[tid * S_PAD + j] - mx);
            S[tid * S_PAD + j] = e;
            sum += e;
        }
        float inv = 1.f / sum;
        for (int j = 0; j < N_TOK; ++j) S[tid * S_PAD + j] *= inv;
    }
    __syncthreads();

    // ---- O = S @ v, store to act[b][row][h*32 + tx] ----
    {
        float acc[7] = {0.f, 0.f, 0.f, 0.f, 0.f, 0.f, 0.f};
        for (int kk = 0; kk < N_TOK; ++kk) {
            float vv = vs[kk * PAD33 + tx];  // conflict-free
#pragma unroll
            for (int r = 0; r < 7; ++r)
                acc[r] = fmaf(S[rwc[r] * S_PAD + kk], vv, acc[r]);  // broadcast
        }
#pragma unroll
        for (int r = 0; r < 7; ++r)
            if (row[r] < N_TOK)
                act[(size_t)b * N_TOK * C_DIM + row[r] * C_DIM + h * HD + tx] = acc[r];
    }
}

// Kernel 2: in-place projection  io[b] = act[b] @ proj_w^T + proj_b
__global__ __launch_bounds__(256) void proj_kernel(
    const float* __restrict__ proj_w,
    const float* __restrict__ proj_b,
    float* __restrict__ io)
{
    const int b   = blockIdx.x;
    const int tid = threadIdx.x;
    __shared__ __align__(16) float xs[N_TOK * C_DIM];
    __shared__ __align__(16) float wT[C_DIM * PAD33];

    {
        const float4* xg  = (const float4*)(io + (size_t)b * N_TOK * C_DIM);
        float4*       xs4 = (float4*)xs;
        for (int i = tid; i < N_TOK * C_DIM / 4; i += 256) xs4[i] = xg[i];
    }

    const int tx = tid & 31;
    const int ty = tid >> 5;
    int row[7], rwc[7];
#pragma unroll
    for (int r = 0; r < 7; ++r) {
        row[r] = ty + 8 * r;
        rwc[r] = row[r] < N_TOK ? row[r] : N_TOK - 1;
    }

    for (int ch = 0; ch < 4; ++ch) {   // 4 chunks of 32 output channels
        __syncthreads();               // covers xs staging (ch=0) + wT reuse
        const float4* wg = (const float4*)(proj_w + (size_t)ch * HD * C_DIM);
        for (int i = tid; i < HD * C_DIM / 4; i += 256) {
            int j  = i >> 5;
            int kk = (i & 31) << 2;
            float4 wv = wg[i];
            wT[(kk + 0) * PAD33 + j] = wv.x;
            wT[(kk + 1) * PAD33 + j] = wv.y;
            wT[(kk + 2) * PAD33 + j] = wv.z;
            wT[(kk + 3) * PAD33 + j] = wv.w;
        }
        __syncthreads();

        float acc[7] = {0.f, 0.f, 0.f, 0.f, 0.f, 0.f, 0.f};
        for (int kk = 0; kk < C_DIM; kk += 4) {
            float w0 = wT[(kk + 0) * PAD33 + tx];
            float w1 = wT[(kk + 1) * PAD33 + tx];
            float w2 = wT[(kk + 2) * PAD33 + tx];
            float w3 = wT[(kk + 3) * PAD33 + tx];
#pragma unroll
            for (int r = 0; r < 7; ++r) {
                float4 xv = *(const float4*)&xs[rwc[r] * C_DIM + kk];
                acc[r] = fmaf(xv.x, w0, acc[r]);
                acc[r] = fmaf(xv.y, w1, acc[r]);
                acc[r] = fmaf(xv.z, w2, acc[r]);
                acc[r] = fmaf(xv.w, w3, acc[r]);
            }
        }
        float bias = proj_b[ch * HD + tx];
#pragma unroll
        for (int r = 0; r < 7; ++r)
            if (row[r] < N_TOK)
                io[(size_t)b * N_TOK * C_DIM + row[r] * C_DIM + ch * HD + tx] =
                    acc[r] + bias;
    }
}

extern "C" void kernel_launch(void* const* d_in, const int* in_sizes, int n_in,
                              void* d_out, int out_size, void* d_ws, size_t ws_size,
                              hipStream_t stream) {
    const float* x      = (const float*)d_in[0];
    const float* mask   = (const float*)d_in[1];
    const float* qkv_w  = (const float*)d_in[2];
    const float* qkv_b  = (const float*)d_in[3];
    const float* proj_w = (const float*)d_in[4];
    const float* proj_b = (const float*)d_in[5];
    float* out = (float*)d_out;

    attn_fused<<<dim3(B_TOT, 4), 256, 0, stream>>>(x, mask, qkv_w, qkv_b, out);
    proj_kernel<<<B_TOT, 256, 0, stream>>>(proj_w, proj_b, out);
}

// Round 2
// 305.802 us; speedup vs baseline: 5.9597x; 5.9597x over previous
//
#include <hip/hip_runtime.h>
#include <hip/hip_bf16.h>

#define N_TOK 49
#define C_DIM 128
#define HD 32
#define SCALE 0.17677669529663687f

typedef __attribute__((ext_vector_type(8))) short frag8;
typedef __attribute__((ext_vector_type(4))) float f32x4;

// ---- LDS layout (units: ushort/bf16, 2 B) ----
// XBF: x staged as bf16, 64 rows x 136 (rows 49..63 zeroed). Reused as `act`
//      (concat-head attention output) for the fused proj GEMM.
// MSK: mask[b%64] as bf16, 49 x 52.
// Per head (wave): Q[64x40], K[64x40], Vt[32x72] (V transposed: [ch][tok]).
//      P (softmax probs, [tok][tok] 64x72) overlays Q+K after frags are in regs.
// Total = 40960 ushorts = 80 KB exactly -> 2 blocks/CU.
#define XBF_OFF 0
#define XBF_STR 136
#define MSK_OFF 8704
#define MSK_STR 52
#define HEAD_OFF 11264
#define HEAD_SZ 7424
#define Q_STR 40
#define VT_STR 72
#define P_STR 72
#define SMEM_TOT 40960

__device__ __forceinline__ unsigned short f2b(float x) {
    __hip_bfloat16 h = __float2bfloat16(x);
    return __builtin_bit_cast(unsigned short, h);
}
__device__ __forceinline__ float b2f(unsigned short u) {
    return __builtin_bit_cast(float, (unsigned)u << 16);
}

// Prep: fp32 weights -> bf16 in workspace. [0,49152): qkv_w, [49152,65536): proj_w
__global__ void convert_weights(const float* __restrict__ qkvw,
                                const float* __restrict__ projw,
                                unsigned short* __restrict__ wbf) {
    int i = blockIdx.x * 256 + threadIdx.x;
    float v = (i < 49152) ? qkvw[i] : projw[i - 49152];
    wbf[i] = f2b(v);
}

__global__ __launch_bounds__(256) void attn_mfma(
    const float* __restrict__ x,
    const float* __restrict__ mask,
    const float* __restrict__ qkv_b,
    const float* __restrict__ proj_b,
    const unsigned short* __restrict__ wq,   // bf16 qkv_w [384][128] + proj_w [128][128]
    float* __restrict__ out)
{
    __shared__ __align__(16) unsigned short sm[SMEM_TOT];

    const int b = blockIdx.x, tid = threadIdx.x;
    const int w = tid >> 6;          // wave id == head
    const int lane = tid & 63;
    const int n16 = lane & 15;
    const int q = lane >> 4;         // quad

    // ---- stage x[b] -> bf16 LDS (+zero pad rows), mask -> bf16 LDS ----
    {
        const float4* xg = (const float4*)(x + (size_t)b * 6272);
        for (int i = tid; i < 1568; i += 256) {
            float4 v = xg[i];
            int row = i >> 5, col = (i & 31) << 2;
            ushort4 pk;
            pk.x = f2b(v.x); pk.y = f2b(v.y); pk.z = f2b(v.z); pk.w = f2b(v.w);
            *(ushort4*)&sm[XBF_OFF + row * XBF_STR + col] = pk;
        }
        for (int i = tid; i < 15 * XBF_STR; i += 256)
            sm[XBF_OFF + 49 * XBF_STR + i] = 0;
        const float* mg = mask + (size_t)(b & 63) * 2401;
        for (int i = tid; i < 2401; i += 256) {
            int r = i / 49, c = i - r * 49;
            sm[MSK_OFF + r * MSK_STR + c] = f2b(mg[i]);
        }
    }
    __syncthreads();

    const int Qb = HEAD_OFF + w * HEAD_SZ;
    const int Kb = Qb + 2560;
    const int Vb = Qb + 5120;
    const int Pb = Qb;  // overlay Q+K

    // ---- Phase A: QKV for head w.  A-frags from xbf (cached), B from global bf16 w ----
    frag8 a[4][4];
#pragma unroll
    for (int mt = 0; mt < 4; ++mt)
#pragma unroll
        for (int ks = 0; ks < 4; ++ks)
            a[mt][ks] = *(const frag8*)&sm[XBF_OFF + (mt * 16 + n16) * XBF_STR + ks * 32 + q * 8];

#pragma unroll
    for (int mat = 0; mat < 3; ++mat) {
#pragma unroll
        for (int nt = 0; nt < 2; ++nt) {
            const unsigned short* wrow = wq + (size_t)(mat * C_DIM + w * HD + nt * 16 + n16) * C_DIM;
            frag8 bf[4];
#pragma unroll
            for (int ks = 0; ks < 4; ++ks) bf[ks] = *(const frag8*)(wrow + ks * 32 + q * 8);
            float bias = qkv_b[mat * C_DIM + w * HD + nt * 16 + n16];
#pragma unroll
            for (int mt = 0; mt < 4; ++mt) {
                f32x4 acc = {0.f, 0.f, 0.f, 0.f};
#pragma unroll
                for (int ks = 0; ks < 4; ++ks)
                    acc = __builtin_amdgcn_mfma_f32_16x16x32_bf16(a[mt][ks], bf[ks], acc, 0, 0, 0);
                // C-layout: col = n16 (channel), rows = mt*16 + q*4 + r (token)
                if (mat == 2) {
                    // V: write transposed Vt[ch][tok]; 4 consecutive toks -> packed b64
                    ushort4 pk;
                    pk.x = f2b(acc[0] + bias); pk.y = f2b(acc[1] + bias);
                    pk.z = f2b(acc[2] + bias); pk.w = f2b(acc[3] + bias);
                    *(ushort4*)&sm[Vb + (nt * 16 + n16) * VT_STR + mt * 16 + q * 4] = pk;
                } else {
                    const int base = (mat == 0) ? Qb : Kb;
                    const float sc = (mat == 0) ? SCALE : 1.f;
#pragma unroll
                    for (int r = 0; r < 4; ++r)
                        sm[base + (mt * 16 + q * 4 + r) * Q_STR + nt * 16 + n16] =
                            f2b((acc[r] + bias) * sc);
                }
            }
        }
    }

    // ---- Phase B: S = Q K^T, C initialized with mask ----
    frag8 qf[4], kf[4];
#pragma unroll
    for (int t = 0; t < 4; ++t) {
        qf[t] = *(const frag8*)&sm[Qb + (t * 16 + n16) * Q_STR + q * 8];
        kf[t] = *(const frag8*)&sm[Kb + (t * 16 + n16) * Q_STR + q * 8];
    }
    f32x4 s[4][4];
#pragma unroll
    for (int mt = 0; mt < 4; ++mt)
#pragma unroll
        for (int nt = 0; nt < 4; ++nt) {
            int cc = min(nt * 16 + n16, 48);
#pragma unroll
            for (int r = 0; r < 4; ++r) {
                int rc = min(mt * 16 + q * 4 + r, 48);
                s[mt][nt][r] = b2f(sm[MSK_OFF + rc * MSK_STR + cc]);
            }
            s[mt][nt] = __builtin_amdgcn_mfma_f32_16x16x32_bf16(qf[mt], kf[nt], s[mt][nt], 0, 0, 0);
        }

    // ---- in-register softmax: each row lives in one 16-lane quad across 4 nt tiles ----
#pragma unroll
    for (int mt = 0; mt < 4; ++mt) {
#pragma unroll
        for (int r = 0; r < 4; ++r) {
            float mx = -1e30f;
#pragma unroll
            for (int nt = 0; nt < 4; ++nt)
                if (nt * 16 + n16 < 49) mx = fmaxf(mx, s[mt][nt][r]);
#pragma unroll
            for (int d = 1; d < 16; d <<= 1) mx = fmaxf(mx, __shfl_xor(mx, d));
            float sum = 0.f;
#pragma unroll
            for (int nt = 0; nt < 4; ++nt) {
                float e = (nt * 16 + n16 < 49) ? __expf(s[mt][nt][r] - mx) : 0.f;
                s[mt][nt][r] = e;
                sum += e;
            }
#pragma unroll
            for (int d = 1; d < 16; d <<= 1) sum += __shfl_xor(sum, d);
            float inv = __builtin_amdgcn_rcpf(sum);
#pragma unroll
            for (int nt = 0; nt < 4; ++nt) s[mt][nt][r] *= inv;
        }
    }

    // ---- P -> LDS (overlay Q+K), layout [tok_m][tok_k] for A-operand reads ----
#pragma unroll
    for (int mt = 0; mt < 4; ++mt)
#pragma unroll
        for (int nt = 0; nt < 4; ++nt)
#pragma unroll
            for (int r = 0; r < 4; ++r)
                sm[Pb + (mt * 16 + q * 4 + r) * P_STR + nt * 16 + n16] = f2b(s[mt][nt][r]);

    // ---- Phase C: O = P V ----
    frag8 vf[2][2];
#pragma unroll
    for (int nt = 0; nt < 2; ++nt)
#pragma unroll
        for (int ks = 0; ks < 2; ++ks)
            vf[nt][ks] = *(const frag8*)&sm[Vb + (nt * 16 + n16) * VT_STR + ks * 32 + q * 8];
    f32x4 o[4][2];
#pragma unroll
    for (int mt = 0; mt < 4; ++mt)
#pragma unroll
        for (int nt = 0; nt < 2; ++nt) o[mt][nt] = (f32x4){0.f, 0.f, 0.f, 0.f};
#pragma unroll
    for (int mt = 0; mt < 4; ++mt)
#pragma unroll
        for (int ks = 0; ks < 2; ++ks) {
            frag8 pf = *(const frag8*)&sm[Pb + (mt * 16 + n16) * P_STR + ks * 32 + q * 8];
#pragma unroll
            for (int nt = 0; nt < 2; ++nt)
                o[mt][nt] = __builtin_amdgcn_mfma_f32_16x16x32_bf16(pf, vf[nt][ks], o[mt][nt], 0, 0, 0);
        }

    // ---- write O into act (= xbf region) as bf16, then fused proj GEMM ----
    __syncthreads();  // all waves done reading xbf
#pragma unroll
    for (int mt = 0; mt < 4; ++mt)
#pragma unroll
        for (int nt = 0; nt < 2; ++nt)
#pragma unroll
            for (int r = 0; r < 4; ++r)
                sm[XBF_OFF + (mt * 16 + q * 4 + r) * XBF_STR + w * HD + nt * 16 + n16] =
                    f2b(o[mt][nt][r]);
    __syncthreads();

    // ---- Phase D: out = act @ proj_w^T + proj_b; wave w -> out channels w*32..+32 ----
    frag8 af[4][4];
#pragma unroll
    for (int mt = 0; mt < 4; ++mt)
#pragma unroll
        for (int ks = 0; ks < 4; ++ks)
            af[mt][ks] = *(const frag8*)&sm[XBF_OFF + (mt * 16 + n16) * XBF_STR + ks * 32 + q * 8];

    const unsigned short* pw = wq + 49152;
    float* outb = out + (size_t)b * 6272;
#pragma unroll
    for (int nt = 0; nt < 2; ++nt) {
        const unsigned short* wrow = pw + (size_t)(w * HD + nt * 16 + n16) * C_DIM;
        frag8 bf[4];
#pragma unroll
        for (int ks = 0; ks < 4; ++ks) bf[ks] = *(const frag8*)(wrow + ks * 32 + q * 8);
        float bias = proj_b[w * HD + nt * 16 + n16];
#pragma unroll
        for (int mt = 0; mt < 4; ++mt) {
            f32x4 acc = {0.f, 0.f, 0.f, 0.f};
#pragma unroll
            for (int ks = 0; ks < 4; ++ks)
                acc = __builtin_amdgcn_mfma_f32_16x16x32_bf16(af[mt][ks], bf[ks], acc, 0, 0, 0);
#pragma unroll
            for (int r = 0; r < 4; ++r) {
                int row = mt * 16 + q * 4 + r;
                if (row < 49) outb[row * C_DIM + w * HD + nt * 16 + n16] = acc[r] + bias;
            }
        }
    }
}

extern "C" void kernel_launch(void* const* d_in, const int* in_sizes, int n_in,
                              void* d_out, int out_size, void* d_ws, size_t ws_size,
                              hipStream_t stream) {
    const float* x      = (const float*)d_in[0];
    const float* mask   = (const float*)d_in[1];
    const float* qkv_w  = (const float*)d_in[2];
    const float* qkv_b  = (const float*)d_in[3];
    const float* proj_w = (const float*)d_in[4];
    const float* proj_b = (const float*)d_in[5];

    unsigned short* wbf = (unsigned short*)d_ws;  // needs 131072 B
    convert_weights<<<256, 256, 0, stream>>>(qkv_w, proj_w, wbf);
    attn_mfma<<<4096, 256, 0, stream>>>(x, mask, qkv_b, proj_b, wbf, (float*)d_out);
}

// Round 3
// 294.334 us; speedup vs baseline: 6.1919x; 1.0390x over previous
//
#include <hip/hip_runtime.h>
#include <hip/hip_bf16.h>

#define C_DIM 128
#define HD 32
#define SCALE 0.17677669529663687f

typedef __attribute__((ext_vector_type(8))) short frag8;
typedef __attribute__((ext_vector_type(4))) float f32x4;

// ---- LDS layout (units: ushort/bf16) ----
// XBF: x as bf16, 64 x 136 (rows 49..63 zero). Reused as `act` for proj.
// MSK: mask[b%64] bf16, 49 x 52.
// Per head: Q[64x40], K[64x40], Vt[32x72]; P[64x72] overlays Q+K.
// Total 40960 ushorts = 80 KB -> 2 blocks/CU; 512 thr/block -> 16 waves/CU.
#define XBF_OFF 0
#define XBF_STR 136
#define MSK_OFF 8704
#define MSK_STR 52
#define HEAD_OFF 11264
#define HEAD_SZ 7424
#define Q_STR 40
#define VT_STR 72
#define P_STR 72
#define SMEM_TOT 40960

__device__ __forceinline__ unsigned short f2b(float x) {
    __hip_bfloat16 h = __float2bfloat16(x);
    return __builtin_bit_cast(unsigned short, h);
}
__device__ __forceinline__ float b2f(unsigned short u) {
    return __builtin_bit_cast(float, (unsigned)u << 16);
}

// fp32 weights -> bf16 ws: [0,49152) qkv_w, [49152,65536) proj_w. 16384 float4s.
__global__ void convert_weights(const float4* __restrict__ qkvw,
                                const float4* __restrict__ projw,
                                ushort4* __restrict__ wbf) {
    int i = blockIdx.x * 256 + threadIdx.x;
    float4 v = (i < 12288) ? qkvw[i] : projw[i - 12288];
    ushort4 p;
    p.x = f2b(v.x); p.y = f2b(v.y); p.z = f2b(v.z); p.w = f2b(v.w);
    wbf[i] = p;
}

__global__ __launch_bounds__(512, 4) void attn_mfma(
    const float* __restrict__ x,
    const float* __restrict__ mask,
    const float* __restrict__ qkv_b,
    const float* __restrict__ proj_b,
    const unsigned short* __restrict__ wq,   // bf16 qkv_w + proj_w
    float* __restrict__ out)
{
    __shared__ __align__(16) unsigned short sm[SMEM_TOT];

    const int b = blockIdx.x, tid = threadIdx.x;
    const int wave = tid >> 6;
    const int h    = wave >> 1;     // head
    const int half = wave & 1;      // M-half: rows [half*32, half*32+32)
    const int lane = tid & 63;
    const int n16  = lane & 15;
    const int q    = lane >> 4;

    // ---- stage x[b] -> bf16 (+zero pad rows), mask -> bf16 ----
    {
        const float4* xg = (const float4*)(x + (size_t)b * 6272);
        for (int i = tid; i < 1568; i += 512) {
            float4 v = xg[i];
            int row = i >> 5, col = (i & 31) << 2;
            ushort4 pk;
            pk.x = f2b(v.x); pk.y = f2b(v.y); pk.z = f2b(v.z); pk.w = f2b(v.w);
            *(ushort4*)&sm[XBF_OFF + row * XBF_STR + col] = pk;
        }
        for (int i = tid; i < 15 * XBF_STR; i += 512)
            sm[XBF_OFF + 49 * XBF_STR + i] = 0;
        const float* mg = mask + (size_t)(b & 63) * 2401;
        for (int i = tid; i < 2401; i += 512) {
            int r = i / 49, c = i - r * 49;
            sm[MSK_OFF + r * MSK_STR + c] = f2b(mg[i]);
        }
    }
    __syncthreads();  // (1)

    const int Qb = HEAD_OFF + h * HEAD_SZ;
    const int Kb = Qb + 2560;
    const int Vb = Qb + 5120;
    const int Pb = Qb;  // overlay Q+K

    // ---- A-frags for this wave's M-half (rows (half*2+mt)*16 + n16) ----
    frag8 a[2][4];
#pragma unroll
    for (int mt = 0; mt < 2; ++mt)
#pragma unroll
        for (int ks = 0; ks < 4; ++ks)
            a[mt][ks] = *(const frag8*)&sm[XBF_OFF + ((half * 2 + mt) * 16 + n16) * XBF_STR + ks * 32 + q * 8];

    // ---- Phase A: QKV for head h, M-half rows ----
#pragma unroll
    for (int mat = 0; mat < 3; ++mat) {
#pragma unroll
        for (int nt = 0; nt < 2; ++nt) {
            const unsigned short* wrow = wq + (size_t)(mat * C_DIM + h * HD + nt * 16 + n16) * C_DIM;
            frag8 bf[4];
#pragma unroll
            for (int ks = 0; ks < 4; ++ks) bf[ks] = *(const frag8*)(wrow + ks * 32 + q * 8);
            float bias = qkv_b[mat * C_DIM + h * HD + nt * 16 + n16];
#pragma unroll
            for (int mt = 0; mt < 2; ++mt) {
                const int gm = half * 2 + mt;
                f32x4 acc = {0.f, 0.f, 0.f, 0.f};
#pragma unroll
                for (int ks = 0; ks < 4; ++ks)
                    acc = __builtin_amdgcn_mfma_f32_16x16x32_bf16(a[mt][ks], bf[ks], acc, 0, 0, 0);
                if (mat == 2) {
                    ushort4 pk;
                    pk.x = f2b(acc[0] + bias); pk.y = f2b(acc[1] + bias);
                    pk.z = f2b(acc[2] + bias); pk.w = f2b(acc[3] + bias);
                    *(ushort4*)&sm[Vb + (nt * 16 + n16) * VT_STR + gm * 16 + q * 4] = pk;
                } else {
                    const int base = (mat == 0) ? Qb : Kb;
                    const float sc = (mat == 0) ? SCALE : 1.f;
#pragma unroll
                    for (int r = 0; r < 4; ++r)
                        sm[base + (gm * 16 + q * 4 + r) * Q_STR + nt * 16 + n16] =
                            f2b((acc[r] + bias) * sc);
                }
            }
        }
    }
    __syncthreads();  // (2) Q/K/V complete across wave pair

    // ---- Phase B: S = Q K^T (+mask in C) ----
    frag8 qf[2], kf[4];
#pragma unroll
    for (int mt = 0; mt < 2; ++mt)
        qf[mt] = *(const frag8*)&sm[Qb + ((half * 2 + mt) * 16 + n16) * Q_STR + q * 8];
#pragma unroll
    for (int t = 0; t < 4; ++t)
        kf[t] = *(const frag8*)&sm[Kb + (t * 16 + n16) * Q_STR + q * 8];

    f32x4 s[2][4];
#pragma unroll
    for (int mt = 0; mt < 2; ++mt)
#pragma unroll
        for (int nt = 0; nt < 4; ++nt) {
            int cc = min(nt * 16 + n16, 48);
#pragma unroll
            for (int r = 0; r < 4; ++r) {
                int rc = min((half * 2 + mt) * 16 + q * 4 + r, 48);
                s[mt][nt][r] = b2f(sm[MSK_OFF + rc * MSK_STR + cc]);
            }
            s[mt][nt] = __builtin_amdgcn_mfma_f32_16x16x32_bf16(qf[mt], kf[nt], s[mt][nt], 0, 0, 0);
        }

    // ---- softmax: each row in a 16-lane quad across 4 nt tiles ----
#pragma unroll
    for (int mt = 0; mt < 2; ++mt) {
#pragma unroll
        for (int r = 0; r < 4; ++r) {
            float mx = -1e30f;
#pragma unroll
            for (int nt = 0; nt < 4; ++nt)
                if (nt * 16 + n16 < 49) mx = fmaxf(mx, s[mt][nt][r]);
#pragma unroll
            for (int d = 1; d < 16; d <<= 1) mx = fmaxf(mx, __shfl_xor(mx, d));
            float sum = 0.f;
#pragma unroll
            for (int nt = 0; nt < 4; ++nt) {
                float e = (nt * 16 + n16 < 49) ? __expf(s[mt][nt][r] - mx) : 0.f;
                s[mt][nt][r] = e;
                sum += e;
            }
#pragma unroll
            for (int d = 1; d < 16; d <<= 1) sum += __shfl_xor(sum, d);
            float inv = __builtin_amdgcn_rcpf(sum);
#pragma unroll
            for (int nt = 0; nt < 4; ++nt) s[mt][nt][r] *= inv;
        }
    }
    __syncthreads();  // (3) all q/k frags consumed -> safe to overlay P

    // ---- P -> LDS (own M rows) ----
#pragma unroll
    for (int mt = 0; mt < 2; ++mt)
#pragma unroll
        for (int nt = 0; nt < 4; ++nt)
#pragma unroll
            for (int r = 0; r < 4; ++r)
                sm[Pb + ((half * 2 + mt) * 16 + q * 4 + r) * P_STR + nt * 16 + n16] =
                    f2b(s[mt][nt][r]);

    // ---- Phase C: O = P V (own M rows; V all tokens) ----
    frag8 vf[2][2];
#pragma unroll
    for (int nt = 0; nt < 2; ++nt)
#pragma unroll
        for (int ks = 0; ks < 2; ++ks)
            vf[nt][ks] = *(const frag8*)&sm[Vb + (nt * 16 + n16) * VT_STR + ks * 32 + q * 8];
    f32x4 o[2][2];
#pragma unroll
    for (int mt = 0; mt < 2; ++mt)
#pragma unroll
        for (int nt = 0; nt < 2; ++nt) o[mt][nt] = (f32x4){0.f, 0.f, 0.f, 0.f};
#pragma unroll
    for (int mt = 0; mt < 2; ++mt)
#pragma unroll
        for (int ks = 0; ks < 2; ++ks) {
            frag8 pf = *(const frag8*)&sm[Pb + ((half * 2 + mt) * 16 + n16) * P_STR + ks * 32 + q * 8];
#pragma unroll
            for (int nt = 0; nt < 2; ++nt)
                o[mt][nt] = __builtin_amdgcn_mfma_f32_16x16x32_bf16(pf, vf[nt][ks], o[mt][nt], 0, 0, 0);
        }

    // ---- O -> act (xbf region); disjoint per wave, x already consumed ----
#pragma unroll
    for (int mt = 0; mt < 2; ++mt)
#pragma unroll
        for (int nt = 0; nt < 2; ++nt)
#pragma unroll
            for (int r = 0; r < 4; ++r)
                sm[XBF_OFF + ((half * 2 + mt) * 16 + q * 4 + r) * XBF_STR + h * HD + nt * 16 + n16] =
                    f2b(o[mt][nt][r]);
    __syncthreads();  // (4) act complete

    // ---- Phase D: out = act @ proj_w^T + b; wave -> 16 out channels ----
    frag8 af[4][4];
#pragma unroll
    for (int mt = 0; mt < 4; ++mt)
#pragma unroll
        for (int ks = 0; ks < 4; ++ks)
            af[mt][ks] = *(const frag8*)&sm[XBF_OFF + (mt * 16 + n16) * XBF_STR + ks * 32 + q * 8];

    const unsigned short* pw = wq + 49152;
    float* outb = out + (size_t)b * 6272;
    {
        const unsigned short* wrow = pw + (size_t)(wave * 16 + n16) * C_DIM;
        frag8 bf[4];
#pragma unroll
        for (int ks = 0; ks < 4; ++ks) bf[ks] = *(const frag8*)(wrow + ks * 32 + q * 8);
        float bias = proj_b[wave * 16 + n16];
#pragma unroll
        for (int mt = 0; mt < 4; ++mt) {
            f32x4 acc = {0.f, 0.f, 0.f, 0.f};
#pragma unroll
            for (int ks = 0; ks < 4; ++ks)
                acc = __builtin_amdgcn_mfma_f32_16x16x32_bf16(af[mt][ks], bf[ks], acc, 0, 0, 0);
#pragma unroll
            for (int r = 0; r < 4; ++r) {
                int row = mt * 16 + q * 4 + r;
                if (row < 49) outb[row * C_DIM + wave * 16 + n16] = acc[r] + bias;
            }
        }
    }
}

extern "C" void kernel_launch(void* const* d_in, const int* in_sizes, int n_in,
                              void* d_out, int out_size, void* d_ws, size_t ws_size,
                              hipStream_t stream) {
    const float* x      = (const float*)d_in[0];
    const float* mask   = (const float*)d_in[1];
    const float* qkv_b  = (const float*)d_in[3];
    const float* proj_b = (const float*)d_in[5];

    unsigned short* wbf = (unsigned short*)d_ws;  // 131072 B
    convert_weights<<<64, 256, 0, stream>>>((const float4*)d_in[2],
                                            (const float4*)d_in[4],
                                            (ushort4*)wbf);
    attn_mfma<<<4096, 512, 0, stream>>>(x, mask, qkv_b, proj_b, wbf, (float*)d_out);
}

// Round 6
// 293.084 us; speedup vs baseline: 6.2183x; 1.0043x over previous
//
#include <hip/hip_runtime.h>
#include <hip/hip_bf16.h>

#define C_DIM 128
#define SCALE 0.17677669529663687f

typedef __attribute__((ext_vector_type(8))) short frag8;
typedef __attribute__((ext_vector_type(4))) float f32x4;

// ---- LDS (ushort units), 29696 total = 58 KB -> 2 blocks/CU ----
// 4 head regions x 7424: Q[64x40] K[64x40] Vt[32x72] (V needs 64 token cols!).
// P(64x72 = 4608) overlays Q+K (5120). XBF (x bf16, 64x136, rows>=49 zeroed)
// overlays heads 0/1 at [0,8704); act reuses the same place in the epilogue.
#define HEAD_SZ 7424
#define Q_STR 40
#define VT_STR 72
#define P_STR 72
#define XBF_STR 136
#define SMEM_TOT 29696

__device__ __forceinline__ unsigned short f2b(float x) {
    __hip_bfloat16 h = __float2bfloat16(x);
    return __builtin_bit_cast(unsigned short, h);
}
__device__ __forceinline__ unsigned pk2(float a, float b) {
    return ((unsigned)f2b(b) << 16) | (unsigned)f2b(a);
}

// fp32 weights -> bf16 ws: [0,49152) qkv_w, [49152,65536) proj_w
__global__ void convert_weights(const float4* __restrict__ qkvw,
                                const float4* __restrict__ projw,
                                ushort4* __restrict__ wbf) {
    int i = blockIdx.x * 256 + threadIdx.x;
    float4 v = (i < 12288) ? qkvw[i] : projw[i - 12288];
    ushort4 p;
    p.x = f2b(v.x); p.y = f2b(v.y); p.z = f2b(v.z); p.w = f2b(v.w);
    wbf[i] = p;
}

__global__ __launch_bounds__(512, 4) void attn_mfma(
    const float* __restrict__ x,
    const float* __restrict__ mask,
    const float* __restrict__ qkv_b,
    const float* __restrict__ proj_b,
    const unsigned short* __restrict__ wq,
    float* __restrict__ out)
{
    __shared__ __align__(16) unsigned short sm[SMEM_TOT];

    const int b = blockIdx.x, tid = threadIdx.x;
    const int wave = tid >> 6;
    const int h    = wave >> 1;
    const int half = wave & 1;          // token half: rows [half*32, half*32+32)
    const int lane = tid & 63;
    const int n16  = lane & 15;
    const int q    = lane >> 4;

    // ---- stage x[b] -> bf16 XBF (+zero pad rows 49..63) ----
    {
        const float4* xg = (const float4*)(x + (size_t)b * 6272);
        for (int i = tid; i < 1568; i += 512) {
            float4 v = xg[i];
            int row = i >> 5, col = (i & 31) << 2;
            uint2 pk; pk.x = pk2(v.x, v.y); pk.y = pk2(v.z, v.w);
            *(uint2*)&sm[row * XBF_STR + col] = pk;
        }
        if (tid < 510) *(ushort4*)&sm[49 * XBF_STR + tid * 4] = (ushort4){0, 0, 0, 0};
    }
    __syncthreads();  // (0) x staged

    // ---- x frags: lane n16 -> token (B-op for Q/K, A-op for V) ----
    frag8 xf[2][4];
#pragma unroll
    for (int tt = 0; tt < 2; ++tt)
#pragma unroll
        for (int ks = 0; ks < 4; ++ks)
            xf[tt][ks] = *(const frag8*)&sm[((half * 2 + tt) * 16 + n16) * XBF_STR + ks * 32 + q * 8];
    __syncthreads();  // (1) XBF consumed -> head regions writable

    const int Qb = h * HEAD_SZ, Kb = Qb + 2560, Vb = Qb + 5120, Pb = Qb;

    // ---- Phase A: QKV (swapped operands -> packed epilogue writes) ----
#pragma unroll
    for (int mat = 0; mat < 3; ++mat) {
#pragma unroll
        for (int ct = 0; ct < 2; ++ct) {
            const unsigned short* wrow = wq + (size_t)(mat * C_DIM + h * 32 + ct * 16 + n16) * C_DIM;
            frag8 wf[4];
#pragma unroll
            for (int ks = 0; ks < 4; ++ks) wf[ks] = *(const frag8*)(wrow + ks * 32 + q * 8);
            if (mat < 2) {
                // D = W x^T: row = out_ch (q*4+r), col = tok (n16) -> pack 4 ch
                float4 b4 = *(const float4*)(qkv_b + mat * C_DIM + h * 32 + ct * 16 + q * 4);
                const float sc = (mat == 0) ? SCALE : 1.f;
                const int base = (mat == 0) ? Qb : Kb;
#pragma unroll
                for (int tt = 0; tt < 2; ++tt) {
                    f32x4 acc = {0.f, 0.f, 0.f, 0.f};
#pragma unroll
                    for (int ks = 0; ks < 4; ++ks)
                        acc = __builtin_amdgcn_mfma_f32_16x16x32_bf16(wf[ks], xf[tt][ks], acc, 0, 0, 0);
                    uint2 pk;
                    pk.x = pk2((acc[0] + b4.x) * sc, (acc[1] + b4.y) * sc);
                    pk.y = pk2((acc[2] + b4.z) * sc, (acc[3] + b4.w) * sc);
                    *(uint2*)&sm[base + ((half * 2 + tt) * 16 + n16) * Q_STR + ct * 16 + q * 4] = pk;
                }
            } else {
                // V: D = x W^T: row = tok (q*4+r), col = ch (n16) -> Vt[ch][tok] packed
                float bias = qkv_b[2 * C_DIM + h * 32 + ct * 16 + n16];
#pragma unroll
                for (int tt = 0; tt < 2; ++tt) {
                    f32x4 acc = {0.f, 0.f, 0.f, 0.f};
#pragma unroll
                    for (int ks = 0; ks < 4; ++ks)
                        acc = __builtin_amdgcn_mfma_f32_16x16x32_bf16(xf[tt][ks], wf[ks], acc, 0, 0, 0);
                    uint2 pk;
                    pk.x = pk2(acc[0] + bias, acc[1] + bias);
                    pk.y = pk2(acc[2] + bias, acc[3] + bias);
                    *(uint2*)&sm[Vb + (ct * 16 + n16) * VT_STR + (half * 2 + tt) * 16 + q * 4] = pk;
                }
            }
        }
    }
    __syncthreads();  // (2) Q/K/V complete

    // ---- Phase B: S^T = K Q^T; fp32 mask (global) is the C initializer ----
    frag8 qf[2], kf[4];
#pragma unroll
    for (int it = 0; it < 2; ++it)
        qf[it] = *(const frag8*)&sm[Qb + ((half * 2 + it) * 16 + n16) * Q_STR + q * 8];
#pragma unroll
    for (int jt = 0; jt < 4; ++jt)
        kf[jt] = *(const frag8*)&sm[Kb + (jt * 16 + n16) * Q_STR + q * 8];
    __syncthreads();  // (3) all frag reads done -> P may overlay Q/K

    const float* mrow = mask + (size_t)(b & 63) * 2401;
    int ii[2];
#pragma unroll
    for (int it = 0; it < 2; ++it) ii[it] = min(half * 32 + it * 16 + n16, 48);

    f32x4 s[4][2];
#pragma unroll
    for (int it = 0; it < 2; ++it) {
#pragma unroll
        for (int jt = 0; jt < 3; ++jt) {  // j = jt*16+q*4+r <= 47: exact
            const float* mp = mrow + ii[it] * 49 + jt * 16 + q * 4;
            s[jt][it] = (f32x4){mp[0], mp[1], mp[2], mp[3]};
        }
        float m48 = (q == 0) ? mrow[ii[it] * 49 + 48] : 0.f;  // jt=3: only j=48 real
        s[3][it] = (f32x4){m48, 0.f, 0.f, 0.f};
    }
#pragma unroll
    for (int jt = 0; jt < 4; ++jt)
#pragma unroll
        for (int it = 0; it < 2; ++it)
            s[jt][it] = __builtin_amdgcn_mfma_f32_16x16x32_bf16(kf[jt], qf[it], s[jt][it], 0, 0, 0);

    // ---- softmax over j (in-lane jt/r, cross-quad via 2 shuffles) ----
#pragma unroll
    for (int it = 0; it < 2; ++it) {
        float mx = -1e30f;
#pragma unroll
        for (int jt = 0; jt < 4; ++jt)
#pragma unroll
            for (int r = 0; r < 4; ++r)
                if (jt * 16 + q * 4 + r < 49) mx = fmaxf(mx, s[jt][it][r]);
        mx = fmaxf(mx, __shfl_xor(mx, 16));
        mx = fmaxf(mx, __shfl_xor(mx, 32));
        float sum = 0.f;
#pragma unroll
        for (int jt = 0; jt < 4; ++jt)
#pragma unroll
            for (int r = 0; r < 4; ++r) {
                float e = (jt * 16 + q * 4 + r < 49) ? __expf(s[jt][it][r] - mx) : 0.f;
                s[jt][it][r] = e;
                sum += e;
            }
        sum += __shfl_xor(sum, 16);
        sum += __shfl_xor(sum, 32);
        float inv = __builtin_amdgcn_rcpf(sum);
        // P[tok_i][tok_j], packed along j
#pragma unroll
        for (int jt = 0; jt < 4; ++jt) {
            uint2 pk;
            pk.x = pk2(s[jt][it][0] * inv, s[jt][it][1] * inv);
            pk.y = pk2(s[jt][it][2] * inv, s[jt][it][3] * inv);
            *(uint2*)&sm[Pb + (half * 32 + it * 16 + n16) * P_STR + jt * 16 + q * 4] = pk;
        }
    }

    // ---- Phase C: O^T = Vt P^T (row = ch -> packed act writes) ----
    frag8 vf[2][2];
#pragma unroll
    for (int ct = 0; ct < 2; ++ct)
#pragma unroll
        for (int ks = 0; ks < 2; ++ks)
            vf[ct][ks] = *(const frag8*)&sm[Vb + (ct * 16 + n16) * VT_STR + ks * 32 + q * 8];
    f32x4 o[2][2];
#pragma unroll
    for (int ct = 0; ct < 2; ++ct)
#pragma unroll
        for (int nt = 0; nt < 2; ++nt) o[ct][nt] = (f32x4){0.f, 0.f, 0.f, 0.f};
#pragma unroll
    for (int nt = 0; nt < 2; ++nt)
#pragma unroll
        for (int ks = 0; ks < 2; ++ks) {
            frag8 pf = *(const frag8*)&sm[Pb + ((half * 2 + nt) * 16 + n16) * P_STR + ks * 32 + q * 8];
#pragma unroll
            for (int ct = 0; ct < 2; ++ct)
                o[ct][nt] = __builtin_amdgcn_mfma_f32_16x16x32_bf16(vf[ct][ks], pf, o[ct][nt], 0, 0, 0);
        }
    __syncthreads();  // (4) all P/V reads done -> act may overlay head regions

    // ---- act[tok][128ch] (bf16, stride 136) at sm[0..8704) ----
#pragma unroll
    for (int ct = 0; ct < 2; ++ct)
#pragma unroll
        for (int nt = 0; nt < 2; ++nt) {
            uint2 pk;
            pk.x = pk2(o[ct][nt][0], o[ct][nt][1]);
            pk.y = pk2(o[ct][nt][2], o[ct][nt][3]);
            *(uint2*)&sm[((half * 2 + nt) * 16 + n16) * XBF_STR + h * 32 + ct * 16 + q * 4] = pk;
        }
    __syncthreads();  // (5) act complete

    // ---- Phase D: out^T = W act^T -> float4 global stores ----
    const unsigned short* pw = wq + 49152;
    frag8 wf2[4];
#pragma unroll
    for (int ks = 0; ks < 4; ++ks)
        wf2[ks] = *(const frag8*)(pw + (size_t)(wave * 16 + n16) * C_DIM + ks * 32 + q * 8);
    float4 b4 = *(const float4*)(proj_b + wave * 16 + q * 4);
    float* outb = out + (size_t)b * 6272;
#pragma unroll
    for (int nt = 0; nt < 4; ++nt) {
        f32x4 acc = {0.f, 0.f, 0.f, 0.f};
#pragma unroll
        for (int ks = 0; ks < 4; ++ks) {
            frag8 af = *(const frag8*)&sm[(nt * 16 + n16) * XBF_STR + ks * 32 + q * 8];
            acc = __builtin_amdgcn_mfma_f32_16x16x32_bf16(wf2[ks], af, acc, 0, 0, 0);
        }
        int tok = nt * 16 + n16;
        if (tok < 49)
            *(float4*)&outb[tok * C_DIM + wave * 16 + q * 4] =
                make_float4(acc[0] + b4.x, acc[1] + b4.y, acc[2] + b4.z, acc[3] + b4.w);
    }
}

extern "C" void kernel_launch(void* const* d_in, const int* in_sizes, int n_in,
                              void* d_out, int out_size, void* d_ws, size_t ws_size,
                              hipStream_t stream) {
    const float* x      = (const float*)d_in[0];
    const float* mask   = (const float*)d_in[1];
    const float* qkv_b  = (const float*)d_in[3];
    const float* proj_b = (const float*)d_in[5];

    unsigned short* wbf = (unsigned short*)d_ws;  // 131072 B
    convert_weights<<<64, 256, 0, stream>>>((const float4*)d_in[2],
                                            (const float4*)d_in[4],
                                            (ushort4*)wbf);
    attn_mfma<<<4096, 512, 0, stream>>>(x, mask, qkv_b, proj_b, wbf, (float*)d_out);
}

// Round 7
// 273.323 us; speedup vs baseline: 6.6679x; 1.0723x over previous
//
#include <hip/hip_runtime.h>
#include <hip/hip_bf16.h>

#define C_DIM 128
#define SCALE 0.17677669529663687f

typedef __attribute__((ext_vector_type(8))) short frag8;
typedef __attribute__((ext_vector_type(4))) float f32x4;

// ---- LDS (ushort units), 32016 total = 64.0 KB -> 2 blocks/CU ----
// XACT [0,6800): x as bf16 rows 0..48 (stride 136); act (50 rows, row 49 = trash)
//   overlays it after barrier (2).
// Per head (wave-PRIVATE, no cross-wave hazards): at 6800 + h*6304:
//   Q 50x40 (row 49 trash), K 50x40 (row 49 trash), Vt 32x72 (cols 49..63 garbage,
//   cancelled by P zeros). P 50x72 (3600) overlays Q+K (4000) after qf/kf in regs.
// Pad-token handling: reads clamp row to 48 (real, bounded); writes for pad
// tokens go to trash row 49; softmax guards j<49; P cols >=49 explicitly 0.
#define XACT_STR 136
#define HEAD_OFF 6800
#define HEAD_SZ  6304
#define KOFF 2000
#define VOFF 4000
#define Q_STR 40
#define VT_STR 72
#define P_STR 72
#define SMEM_TOT 32016

__device__ __forceinline__ unsigned short f2b(float x) {
    __hip_bfloat16 h = __float2bfloat16(x);
    return __builtin_bit_cast(unsigned short, h);
}
__device__ __forceinline__ unsigned pk2(float a, float b) {
    return ((unsigned)f2b(b) << 16) | (unsigned)f2b(a);
}

// fp32 weights -> bf16 ws: [0,49152) qkv_w, [49152,65536) proj_w
__global__ void convert_weights(const float4* __restrict__ qkvw,
                                const float4* __restrict__ projw,
                                ushort4* __restrict__ wbf) {
    int i = blockIdx.x * 256 + threadIdx.x;
    float4 v = (i < 12288) ? qkvw[i] : projw[i - 12288];
    ushort4 p;
    p.x = f2b(v.x); p.y = f2b(v.y); p.z = f2b(v.z); p.w = f2b(v.w);
    wbf[i] = p;
}

__global__ __launch_bounds__(256, 2) void attn_mfma(
    const float* __restrict__ x,
    const float* __restrict__ mask,
    const float* __restrict__ qkv_b,
    const float* __restrict__ proj_b,
    const unsigned short* __restrict__ wq,
    float* __restrict__ out)
{
    __shared__ __align__(16) unsigned short sm[SMEM_TOT];

    const int b = blockIdx.x, tid = threadIdx.x;
    const int h    = tid >> 6;   // wave = head, owns the full chain
    const int lane = tid & 63;
    const int n16  = lane & 15;
    const int q    = lane >> 4;

    // ---- hoisted proj weights + biases (overlap x staging latency) ----
    const unsigned short* pw = wq + 49152;
    frag8 wf2[2][4];
#pragma unroll
    for (int ct = 0; ct < 2; ++ct)
#pragma unroll
        for (int ks = 0; ks < 4; ++ks)
            wf2[ct][ks] = *(const frag8*)(pw + (size_t)(h * 32 + ct * 16 + n16) * C_DIM + ks * 32 + q * 8);
    float4 pb4[2];
#pragma unroll
    for (int ct = 0; ct < 2; ++ct)
        pb4[ct] = *(const float4*)(proj_b + h * 32 + ct * 16 + q * 4);

    // ---- stage x[b] rows 0..48 -> bf16 ----
    {
        const float4* xg = (const float4*)(x + (size_t)b * 6272);
        for (int i = tid; i < 1568; i += 256) {
            float4 v = xg[i];
            int row = i >> 5, col = (i & 31) << 2;
            uint2 pk; pk.x = pk2(v.x, v.y); pk.y = pk2(v.z, v.w);
            *(uint2*)&sm[row * XACT_STR + col] = pk;
        }
    }
    __syncthreads();  // (1) x staged

    // ---- x frags, pad rows clamp to row 48 ----
    frag8 xf[4][4];
#pragma unroll
    for (int tt = 0; tt < 4; ++tt)
#pragma unroll
        for (int ks = 0; ks < 4; ++ks)
            xf[tt][ks] = *(const frag8*)&sm[min(tt * 16 + n16, 48) * XACT_STR + ks * 32 + q * 8];
    __syncthreads();  // (2) XACT dead as x -> act overlay allowed later

    const int Hb = HEAD_OFF + h * HEAD_SZ;

    // ---- Phase A: QKV, wave-private epilogues, NO barriers ----
#pragma unroll
    for (int mat = 0; mat < 3; ++mat) {
#pragma unroll
        for (int ct = 0; ct < 2; ++ct) {
            const unsigned short* wrow = wq + (size_t)(mat * C_DIM + h * 32 + ct * 16 + n16) * C_DIM;
            frag8 wf[4];
#pragma unroll
            for (int ks = 0; ks < 4; ++ks) wf[ks] = *(const frag8*)(wrow + ks * 32 + q * 8);
            if (mat < 2) {
                // D = W x^T: row=ch(q*4+r), col=tok(n16) -> Q/K[tok][ch] packed
                float4 b4 = *(const float4*)(qkv_b + mat * C_DIM + h * 32 + ct * 16 + q * 4);
                const float sc = (mat == 0) ? SCALE : 1.f;
                const int base = Hb + ((mat == 0) ? 0 : KOFF);
#pragma unroll
                for (int tt = 0; tt < 4; ++tt) {
                    f32x4 acc = {0.f, 0.f, 0.f, 0.f};
#pragma unroll
                    for (int ks = 0; ks < 4; ++ks)
                        acc = __builtin_amdgcn_mfma_f32_16x16x32_bf16(wf[ks], xf[tt][ks], acc, 0, 0, 0);
                    uint2 pk;
                    pk.x = pk2((acc[0] + b4.x) * sc, (acc[1] + b4.y) * sc);
                    pk.y = pk2((acc[2] + b4.z) * sc, (acc[3] + b4.w) * sc);
                    *(uint2*)&sm[base + min(tt * 16 + n16, 49) * Q_STR + ct * 16 + q * 4] = pk;
                }
            } else {
                // V: D = x W^T: row=tok(q*4+r), col=ch(n16) -> Vt[ch][tok] packed
                float bias = qkv_b[2 * C_DIM + h * 32 + ct * 16 + n16];
#pragma unroll
                for (int tt = 0; tt < 4; ++tt) {
                    f32x4 acc = {0.f, 0.f, 0.f, 0.f};
#pragma unroll
                    for (int ks = 0; ks < 4; ++ks)
                        acc = __builtin_amdgcn_mfma_f32_16x16x32_bf16(xf[tt][ks], wf[ks], acc, 0, 0, 0);
                    uint2 pk;
                    pk.x = pk2(acc[0] + bias, acc[1] + bias);
                    pk.y = pk2(acc[2] + bias, acc[3] + bias);
                    *(uint2*)&sm[Hb + VOFF + (ct * 16 + n16) * VT_STR + tt * 16 + q * 4] = pk;
                }
            }
        }
    }

    // ---- Phase B: S^T = K Q^T, mask (global fp32) as C-init; in-wave order ----
    frag8 qf[4], kf[4];
#pragma unroll
    for (int t = 0; t < 4; ++t) {
        qf[t] = *(const frag8*)&sm[Hb + (t * 16 + n16) * Q_STR + q * 8];
        kf[t] = *(const frag8*)&sm[Hb + KOFF + (t * 16 + n16) * Q_STR + q * 8];
    }
    const float* mrow = mask + (size_t)(b & 63) * 2401;
    f32x4 s[4][4];   // [jt][it]
#pragma unroll
    for (int it = 0; it < 4; ++it) {
        int ii = min(it * 16 + n16, 48);
#pragma unroll
        for (int jt = 0; jt < 3; ++jt) {
            const float* mp = mrow + ii * 49 + jt * 16 + q * 4;
            s[jt][it] = (f32x4){mp[0], mp[1], mp[2], mp[3]};
        }
        float m48 = (q == 0) ? mrow[ii * 49 + 48] : 0.f;
        s[3][it] = (f32x4){m48, 0.f, 0.f, 0.f};
    }
#pragma unroll
    for (int jt = 0; jt < 4; ++jt)
#pragma unroll
        for (int it = 0; it < 4; ++it)
            s[jt][it] = __builtin_amdgcn_mfma_f32_16x16x32_bf16(kf[jt], qf[it], s[jt][it], 0, 0, 0);

    // ---- softmax + P writes (P overlays Q+K; qf/kf already in regs) ----
#pragma unroll
    for (int it = 0; it < 4; ++it) {
        float mx = -1e30f;
#pragma unroll
        for (int jt = 0; jt < 4; ++jt)
#pragma unroll
            for (int r = 0; r < 4; ++r)
                if (jt * 16 + q * 4 + r < 49) mx = fmaxf(mx, s[jt][it][r]);
        mx = fmaxf(mx, __shfl_xor(mx, 16));
        mx = fmaxf(mx, __shfl_xor(mx, 32));
        float sum = 0.f;
#pragma unroll
        for (int jt = 0; jt < 4; ++jt)
#pragma unroll
            for (int r = 0; r < 4; ++r) {
                float e = (jt * 16 + q * 4 + r < 49) ? __expf(s[jt][it][r] - mx) : 0.f;
                s[jt][it][r] = e;
                sum += e;
            }
        sum += __shfl_xor(sum, 16);
        sum += __shfl_xor(sum, 32);
        float inv = __builtin_amdgcn_rcpf(sum);
#pragma unroll
        for (int jt = 0; jt < 4; ++jt) {
            uint2 pk;
            pk.x = pk2(s[jt][it][0] * inv, s[jt][it][1] * inv);
            pk.y = pk2(s[jt][it][2] * inv, s[jt][it][3] * inv);
            *(uint2*)&sm[Hb + min(it * 16 + n16, 49) * P_STR + jt * 16 + q * 4] = pk;
        }
    }

    // ---- Phase C: O^T = Vt P^T ----
    frag8 vf[2][2];
#pragma unroll
    for (int ct = 0; ct < 2; ++ct)
#pragma unroll
        for (int ks = 0; ks < 2; ++ks)
            vf[ct][ks] = *(const frag8*)&sm[Hb + VOFF + (ct * 16 + n16) * VT_STR + ks * 32 + q * 8];
    f32x4 o[2][4];
#pragma unroll
    for (int ct = 0; ct < 2; ++ct)
#pragma unroll
        for (int nt = 0; nt < 4; ++nt) o[ct][nt] = (f32x4){0.f, 0.f, 0.f, 0.f};
#pragma unroll
    for (int nt = 0; nt < 4; ++nt)
#pragma unroll
        for (int ks = 0; ks < 2; ++ks) {
            frag8 pf = *(const frag8*)&sm[Hb + min(nt * 16 + n16, 49) * P_STR + ks * 32 + q * 8];
#pragma unroll
            for (int ct = 0; ct < 2; ++ct)
                o[ct][nt] = __builtin_amdgcn_mfma_f32_16x16x32_bf16(vf[ct][ks], pf, o[ct][nt], 0, 0, 0);
        }

    // ---- act[tok][128ch] over XACT (row 49 = trash for pad toks) ----
#pragma unroll
    for (int ct = 0; ct < 2; ++ct)
#pragma unroll
        for (int nt = 0; nt < 4; ++nt) {
            uint2 pk;
            pk.x = pk2(o[ct][nt][0], o[ct][nt][1]);
            pk.y = pk2(o[ct][nt][2], o[ct][nt][3]);
            *(uint2*)&sm[min(nt * 16 + n16, 49) * XACT_STR + h * 32 + ct * 16 + q * 4] = pk;
        }
    __syncthreads();  // (3) act complete

    // ---- Phase D: out^T = W act^T -> float4 stores ----
    float* outb = out + (size_t)b * 6272;
#pragma unroll
    for (int nt = 0; nt < 4; ++nt) {
        frag8 af[4];
#pragma unroll
        for (int ks = 0; ks < 4; ++ks)
            af[ks] = *(const frag8*)&sm[min(nt * 16 + n16, 48) * XACT_STR + ks * 32 + q * 8];
        int tok = nt * 16 + n16;
#pragma unroll
        for (int ct = 0; ct < 2; ++ct) {
            f32x4 acc = {0.f, 0.f, 0.f, 0.f};
#pragma unroll
            for (int ks = 0; ks < 4; ++ks)
                acc = __builtin_amdgcn_mfma_f32_16x16x32_bf16(wf2[ct][ks], af[ks], acc, 0, 0, 0);
            if (tok < 49)
                *(float4*)&outb[tok * C_DIM + h * 32 + ct * 16 + q * 4] =
                    make_float4(acc[0] + pb4[ct].x, acc[1] + pb4[ct].y,
                                acc[2] + pb4[ct].z, acc[3] + pb4[ct].w);
        }
    }
}

extern "C" void kernel_launch(void* const* d_in, const int* in_sizes, int n_in,
                              void* d_out, int out_size, void* d_ws, size_t ws_size,
                              hipStream_t stream) {
    const float* x      = (const float*)d_in[0];
    const float* mask   = (const float*)d_in[1];
    const float* qkv_b  = (const float*)d_in[3];
    const float* proj_b = (const float*)d_in[5];

    unsigned short* wbf = (unsigned short*)d_ws;  // 131072 B
    convert_weights<<<64, 256, 0, stream>>>((const float4*)d_in[2],
                                            (const float4*)d_in[4],
                                            (ushort4*)wbf);
    attn_mfma<<<4096, 256, 0, stream>>>(x, mask, qkv_b, proj_b, wbf, (float*)d_out);
}